// Round 6
// baseline (534.447 us; speedup 1.0000x reference)
//
#include <hip/hip_runtime.h>
#include <hip/hip_bf16.h>
#include <cstdint>
#include <cstddef>

// Problem: B=4, S=4096, D=256 two-layer full attention + VAE head. fp32 I/O.
// Strategy: bf16 MFMA everywhere GEMM-shaped; fp32 softmax/epilogue.

#define S_LEN 4096
#define DMODEL 256
#define NBATCH 4
#define MTOT (NBATCH * S_LEN)  // 16384

typedef __bf16 bf16;
typedef __bf16 bf16x8 __attribute__((ext_vector_type(8)));
typedef float f32x4 __attribute__((ext_vector_type(4)));
typedef float f32x16 __attribute__((ext_vector_type(16)));

__device__ __forceinline__ f32x4 mfma16(bf16x8 a, bf16x8 b, f32x4 c) {
  return __builtin_amdgcn_mfma_f32_16x16x32_bf16(a, b, c, 0, 0, 0);
}
__device__ __forceinline__ f32x16 mfma32(bf16x8 a, bf16x8 b, f32x16 c) {
  return __builtin_amdgcn_mfma_f32_32x32x16_bf16(a, b, c, 0, 0, 0);
}

// Async global->LDS, 16B per lane. LDS dest semantics: wave-uniform base + lane*16.
__device__ __forceinline__ void async16(bf16* lds, const bf16* g) {
  __builtin_amdgcn_global_load_lds(
      (const __attribute__((address_space(1))) unsigned int*)g,
      (__attribute__((address_space(3))) unsigned int*)lds, 16, 0, 0);
}

__device__ __forceinline__ unsigned short f2bfbits(float f) {
  return __builtin_bit_cast(unsigned short, (bf16)f);
}

// ---------------- cast kernel (x + 8 weight mats in one launch) ----------------
struct WPtrs { const float* p[8]; };

__global__ void cast_all_kernel(const f32x4* __restrict__ x, WPtrs wp,
                                ushort4* __restrict__ x16, ushort4* __restrict__ w16) {
  int bx = blockIdx.x, t = threadIdx.x;
  const f32x4* src;
  ushort4* dst;
  if (bx < 4096) {
    src = x + (size_t)bx * 256 + t;
    dst = x16 + (size_t)bx * 256 + t;
  } else {
    int r = bx - 4096;
    int m = r >> 6;
    int i = (r & 63) * 256 + t;
    src = (const f32x4*)wp.p[m] + i;
    dst = w16 + (size_t)m * 16384 + i;
  }
  f32x4 v = *src;
  ushort4 o;
  o.x = f2bfbits(v[0]); o.y = f2bfbits(v[1]); o.z = f2bfbits(v[2]); o.w = f2bfbits(v[3]);
  *dst = o;
}

// ---------------- GEMM: out[m][n] = sum_k A[m][k]*W[n][k] + bias[n] ----------------
struct GemmIO {
  const float* bias[3];
  void* out[3];
};

template <typename OutT>
__global__ __launch_bounds__(256, 3) void gemm_kernel(const bf16* __restrict__ A,
                                                      const bf16* __restrict__ Wb, GemmIO io) {
  __shared__ bf16 ldsA[128 * 64];
  __shared__ bf16 ldsB[128 * 64];
  const int t = threadIdx.x;
  const int m0 = blockIdx.x * 128;
  const int n0 = blockIdx.y * 128;
  const bf16* W = Wb + (size_t)blockIdx.z * 65536;
  const int w = t >> 6, l = t & 63, lm = l & 15, q = l >> 4;
  const int wr = (w >> 1) * 64, wc = (w & 1) * 64;

  f32x4 acc[4][4] = {};
#pragma unroll 1
  for (int it = 0; it < 4; ++it) {
    const int k0 = it * 64;
#pragma unroll
    for (int c = 0; c < 4; ++c) {
      int i = c * 256 + t;
      int r = i >> 3, c8 = (i & 7) ^ (r & 7);
      async16(&ldsA[i * 8], A + (size_t)(m0 + r) * 256 + k0 + c8 * 8);
    }
#pragma unroll
    for (int c = 0; c < 4; ++c) {
      int i = c * 256 + t;
      int r = i >> 3, c8 = (i & 7) ^ (r & 7);
      async16(&ldsB[i * 8], W + (size_t)(n0 + r) * 256 + k0 + c8 * 8);
    }
    __syncthreads();
#pragma unroll
    for (int ks = 0; ks < 2; ++ks) {
      bf16x8 af[4], bfr[4];
#pragma unroll
      for (int i = 0; i < 4; ++i) {
        int ra = wr + i * 16 + lm;
        af[i] = *(const bf16x8*)&ldsA[ra * 64 + ((((ks << 2) + q) ^ (ra & 7)) << 3)];
        int rb = wc + i * 16 + lm;
        bfr[i] = *(const bf16x8*)&ldsB[rb * 64 + ((((ks << 2) + q) ^ (rb & 7)) << 3)];
      }
#pragma unroll
      for (int i = 0; i < 4; ++i)
#pragma unroll
        for (int jj = 0; jj < 4; ++jj) acc[i][jj] = mfma16(af[i], bfr[jj], acc[i][jj]);
    }
    __syncthreads();
  }
  const float* bias = io.bias[blockIdx.z];
  OutT* out = (OutT*)io.out[blockIdx.z];
#pragma unroll
  for (int jj = 0; jj < 4; ++jj) {
    int col = n0 + wc + jj * 16 + lm;
    float bv = bias[col];
#pragma unroll
    for (int i = 0; i < 4; ++i) {
      int row = m0 + wr + i * 16 + q * 4;
#pragma unroll
      for (int r = 0; r < 4; ++r)
        out[(size_t)(row + r) * 256 + col] = (OutT)(acc[i][jj][r] + bv);
    }
  }
}

// ---------------- transpose: V [B][S][256] -> Vt [B][256][S] ----------------
__global__ void transpose_kernel(const bf16* __restrict__ src, bf16* __restrict__ dst) {
  __shared__ bf16 tile[64][72];
  int s0 = blockIdx.x * 64, d0 = blockIdx.y * 64;
  size_t boff = (size_t)blockIdx.z * S_LEN * 256;
  size_t boffT = (size_t)blockIdx.z * 256 * S_LEN;
  int t = threadIdx.x;
#pragma unroll
  for (int rep = 0; rep < 16; ++rep) {
    int lin = rep * 256 + t;
    int r = lin >> 6, c = lin & 63;
    tile[r][c] = src[boff + (size_t)(s0 + r) * 256 + d0 + c];
  }
  __syncthreads();
#pragma unroll
  for (int rep = 0; rep < 16; ++rep) {
    int lin = rep * 256 + t;
    int r = lin >> 6, c = lin & 63;
    dst[boffT + (size_t)(d0 + r) * S_LEN + s0 + c] = tile[c][r];
  }
}

// ---------------- flash attention v5: S^T trick, P stays in registers ----------------
// 256 blocks (1/CU), 512 threads = 8 waves = 2/SIMD. BM=64 Q rows, KV tile 128.
// Wave (qg = w&1, sub = w>>1): owns Q rows qg*32.. and KV strip sub*32.. .
//  QK: S^T = mfma32(A=K from LDS, B=Q regs) -> C has lane=q-row, regs=kv-col.
//  exp in regs; in-register kh-half exchange (4 shfl_xor + cndmask) converts S^T
//  C-layout directly to PV A-fragments -- NO P LDS round-trip, NO extra barrier.
//  PV: O_partial[32 q rows x 256 D] += P(regs) x V(LDS), k = own 32 kv only.
//  End: O partials across 4 subs merged via LDS (no-max softmax => plain adds).
// C/D map (verified): col=lane&31, row=(reg&3)+8*(reg>>2)+4*(lane>>5).
// A/B frag: lane = output dim (&31), k = (lane>>5)*8 + j.
__global__ __launch_bounds__(512, 2) void flash_kernel(const bf16* __restrict__ Q,
                                                       const bf16* __restrict__ K,
                                                       const bf16* __restrict__ Vt,
                                                       bf16* __restrict__ O) {
  // K tile: 128 kv-rows x 256 d (32 chunks/row, slot = chunk^(row&31))  = 64KB
  // V tile: 256 d-rows x 128 kv (16 chunks/row, slot = chunk^(d&15))    = 64KB
  // lbuf: [2][4][32] f32 cross-sub l partials                           = 1KB
  __shared__ __align__(16) bf16 smem[66048];
  bf16* ldsK = smem;
  bf16* ldsV = smem + 32768;
  float* lb = (float*)(smem + 65536);

  const int id = blockIdx.x;
  const int xcd = id & 7;
  const int b = xcd >> 1;
  const int qt = (id >> 3) + ((xcd & 1) << 5);  // 0..63

  const bf16* Qb = Q + (size_t)b * S_LEN * 256;
  const bf16* Kb = K + (size_t)b * S_LEN * 256;
  const bf16* Vb = Vt + (size_t)b * 256 * S_LEN;
  bf16* Ob = O + (size_t)b * S_LEN * 256;

  const int t = threadIdx.x, w = t >> 6, lane = t & 63;
  const int m31 = lane & 31, kh = lane >> 5;
  const int qg = w & 1, sub = w >> 1;
  const float CL2 = 0.09016844005556021f;  // log2(e)/sqrt(D) = log2(e)/16

  // staging offsets: 4096 16B-chunks per tile, 8 per thread
  int sld[8], skg[8], svg[8];
#pragma unroll
  for (int it = 0; it < 8; ++it) {
    int c = it * 512 + t;
    sld[it] = c * 8;
    int kr = c >> 5;
    skg[it] = kr * 256 + (((c & 31) ^ (kr & 31)) << 3);
    int d = c >> 4;
    svg[it] = d * S_LEN + (((c & 15) ^ (d & 15)) << 3);
  }
  // K A-frag base: row = sub*32 + m31 (row&31 == m31)
  const int kbrow = (sub * 32 + m31) * 256;
  // V B-frag offsets for kstep 0/1: d-base m31 (d&15 == m31&15), + nt*4096 literal
  int voffk[2];
#pragma unroll
  for (int k2 = 0; k2 < 2; ++k2)
    voffk[k2] = m31 * 128 + ((((sub << 2) + k2 * 2 + kh) ^ (m31 & 15)) << 3);

  // Q B-frags persistent: q-rows qt*64 + qg*32 + m31, k = ks*16 + kh*8 + j
  bf16x8 qf[16];
  {
    const bf16* qrow = Qb + (size_t)(qt * 64 + qg * 32 + m31) * 256 + kh * 8;
#pragma unroll
    for (int ks = 0; ks < 16; ++ks) qf[ks] = *(const bf16x8*)(qrow + ks * 16);
  }

  f32x16 o_acc[8] = {};
  float l_acc = 0.f;

  // prologue: stage K(0)
#pragma unroll
  for (int it = 0; it < 8; ++it) async16(ldsK + sld[it], Kb + skg[it]);

#pragma unroll 1
  for (int j = 0; j < 32; ++j) {
    __syncthreads();  // B1: stageK(j) drained; PV(j-1) done (V free)
    {                 // stage V(j), overlaps QK(j)
      const bf16* vg = Vb + j * 128;
#pragma unroll
      for (int it = 0; it < 8; ++it) async16(ldsV + sld[it], vg + svg[it]);
    }
    // QK(j): S^T strip = K(32 kv) x Q^T(32 q), k = 256
    f32x16 s = {};
#pragma unroll
    for (int ks = 0; ks < 16; ++ks) {
      bf16x8 kf = *(const bf16x8*)(ldsK + kbrow + (((ks * 2 + kh) ^ m31) << 3));
      s = mfma32(kf, qf[ks], s);
    }
    // P = exp2(S*CL2) in regs; l partial; pack to bf16 pairs
    float p[16];
#pragma unroll
    for (int r = 0; r < 16; ++r) {
      p[r] = __builtin_amdgcn_exp2f(s[r] * CL2);
      l_acc += p[r];
    }
    unsigned int pk[8];
#pragma unroll
    for (int r = 0; r < 8; ++r)
      pk[r] = (unsigned int)f2bfbits(p[2 * r]) | ((unsigned int)f2bfbits(p[2 * r + 1]) << 16);
    // kh-half exchange: reg r of kh holds kv (r&3)+8*(r>>2)+4*kh; A-frag needs
    // kv {8*kh..8*kh+7} (+16 per kstep). Swap 4 packed pairs with lane^32.
    unsigned int sA = kh ? pk[0] : pk[2];
    unsigned int sB = kh ? pk[1] : pk[3];
    unsigned int sC = kh ? pk[4] : pk[6];
    unsigned int sD = kh ? pk[5] : pk[7];
    unsigned int rA = __shfl_xor((int)sA, 32, 64);
    unsigned int rB = __shfl_xor((int)sB, 32, 64);
    unsigned int rC = __shfl_xor((int)sC, 32, 64);
    unsigned int rD = __shfl_xor((int)sD, 32, 64);
    union U { unsigned int u[4]; bf16x8 v; } f1, f2;
    f1.u[0] = kh ? rA : pk[0];  f1.u[1] = kh ? rB : pk[1];
    f1.u[2] = kh ? pk[2] : rA;  f1.u[3] = kh ? pk[3] : rB;
    f2.u[0] = kh ? rC : pk[4];  f2.u[1] = kh ? rD : pk[5];
    f2.u[2] = kh ? pk[6] : rC;  f2.u[3] = kh ? pk[7] : rD;

    __syncthreads();  // B2: stageV(j) drained; QK(j) done (K free)
    if (j + 1 < 32) {  // stage K(j+1), overlaps PV(j)
      const bf16* kg = Kb + (size_t)(j + 1) * (128 * 256);
#pragma unroll
      for (int it = 0; it < 8; ++it) async16(ldsK + sld[it], kg + skg[it]);
    }
    // PV(j): own 32 kv, full 256 D
#pragma unroll
    for (int nt = 0; nt < 8; ++nt) {
      bf16x8 v0 = *(const bf16x8*)(ldsV + nt * 4096 + voffk[0]);
      o_acc[nt] = mfma32(f1.v, v0, o_acc[nt]);
      bf16x8 v1 = *(const bf16x8*)(ldsV + nt * 4096 + voffk[1]);
      o_acc[nt] = mfma32(f2.v, v1, o_acc[nt]);
    }
  }

  // ---- cross-sub merge (plain adds; no-max softmax) ----
  l_acc += __shfl_xor(l_acc, 32, 64);  // fold kh halves: l for q=m31
  __syncthreads();                     // last PV's V reads done before smem reuse
  if (kh == 0) lb[(qg * 4 + sub) * 32 + m31] = l_acc;
  float* mb = (float*)smem;  // 4 regions x [nt][reg][lane] f32 = 4 x 32KB
  if (sub & 1) {
    const int rg = (qg << 1) | (sub >> 1);
#pragma unroll
    for (int nt = 0; nt < 8; ++nt)
#pragma unroll
      for (int r = 0; r < 16; ++r) mb[rg * 8192 + (nt * 16 + r) * 64 + lane] = o_acc[nt][r];
  }
  __syncthreads();
  if (!(sub & 1)) {
    const int rg = (qg << 1) | (sub >> 1);
#pragma unroll
    for (int nt = 0; nt < 8; ++nt)
#pragma unroll
      for (int r = 0; r < 16; ++r) o_acc[nt][r] += mb[rg * 8192 + (nt * 16 + r) * 64 + lane];
  }
  __syncthreads();
  if (sub == 2) {
#pragma unroll
    for (int nt = 0; nt < 8; ++nt)
#pragma unroll
      for (int r = 0; r < 16; ++r) mb[qg * 8192 + (nt * 16 + r) * 64 + lane] = o_acc[nt][r];
  }
  __syncthreads();
  if (sub == 0) {
#pragma unroll
    for (int nt = 0; nt < 8; ++nt)
#pragma unroll
      for (int r = 0; r < 16; ++r) o_acc[nt][r] += mb[qg * 8192 + (nt * 16 + r) * 64 + lane];
    float lt = lb[(qg * 4 + 0) * 32 + m31] + lb[(qg * 4 + 1) * 32 + m31] +
               lb[(qg * 4 + 2) * 32 + m31] + lb[(qg * 4 + 3) * 32 + m31];
    float linv[16];
#pragma unroll
    for (int r = 0; r < 16; ++r) {
      const int row = (r & 3) + 8 * (r >> 2) + 4 * kh;
      linv[r] = 1.0f / __shfl(lt, row, 64);
    }
    bf16* orow = Ob + (size_t)(qt * 64 + qg * 32) * 256;
#pragma unroll
    for (int nt = 0; nt < 8; ++nt)
#pragma unroll
      for (int r = 0; r < 16; ++r) {
        const int row = (r & 3) + 8 * (r >> 2) + 4 * kh;
        orow[(size_t)row * 256 + nt * 32 + m31] = (bf16)(o_acc[nt][r] * linv[r]);
      }
  }
}

// ---------------- gate: mean over S then dot Wg + sigmoid ----------------
__global__ __launch_bounds__(256) void gate_partial(const bf16* __restrict__ h,
                                                    float* __restrict__ part) {
  int bb = blockIdx.y;
  const bf16* hb = h + (size_t)bb * S_LEN * 256 + (size_t)blockIdx.x * 64 * 256;
  int t = threadIdx.x;
  float acc = 0.f;
#pragma unroll 4
  for (int s = 0; s < 64; ++s) acc += (float)hb[s * 256 + t];
  part[((size_t)bb * 64 + blockIdx.x) * 256 + t] = acc;
}

__global__ __launch_bounds__(256) void gate_final(const float* __restrict__ part,
                                                  const float* __restrict__ Wg,
                                                  const float* __restrict__ bg,
                                                  float* __restrict__ pg) {
  int bb = blockIdx.x, t = threadIdx.x;
  const float* p = part + (size_t)bb * 64 * 256;
  float acc = 0.f;
#pragma unroll 4
  for (int c = 0; c < 64; ++c) acc += p[c * 256 + t];
  acc *= Wg[t] * (1.0f / 4096.0f);
  __shared__ float red[256];
  red[t] = acc;
  __syncthreads();
  if (t < 64) {
    float a = red[t] + red[t + 64] + red[t + 128] + red[t + 192];
#pragma unroll
    for (int d = 1; d < 64; d <<= 1) a += __shfl_xor(a, d, 64);
    if (t == 0) pg[bb] = 1.0f / (1.0f + __expf(-(a + bg[0])));
  }
}

// ---------------- fused reparam + ELU + residual + LayerNorm ----------------
__global__ __launch_bounds__(64) void epilogue_kernel(const float* __restrict__ x,
                                                      const float* __restrict__ eps,
                                                      const float* __restrict__ mu,
                                                      const float* __restrict__ lv,
                                                      const float* __restrict__ gamma,
                                                      const float* __restrict__ beta,
                                                      float* __restrict__ out) {
  size_t base = (size_t)blockIdx.x * 256;
  int l = threadIdx.x;
  f32x4 xv = ((const f32x4*)(x + base))[l];
  f32x4 ev = ((const f32x4*)(eps + base))[l];
  f32x4 mv = ((const f32x4*)(mu + base))[l];
  f32x4 vv = ((const f32x4*)(lv + base))[l];
  f32x4 y;
  float s = 0.f, s2 = 0.f;
#pragma unroll
  for (int c = 0; c < 4; ++c) {
    float z = mv[c] + ev[c] * __expf(0.5f * vv[c]);
    z = z > 0.f ? z : (__expf(z) - 1.f);
    float yy = xv[c] + z;
    y[c] = yy;
    s += yy;
    s2 += yy * yy;
  }
#pragma unroll
  for (int d = 1; d < 64; d <<= 1) {
    s += __shfl_xor(s, d, 64);
    s2 += __shfl_xor(s2, d, 64);
  }
  float mean = s * (1.f / 256.f);
  float var = s2 * (1.f / 256.f) - mean * mean;
  float rstd = rsqrtf(var + 1e-5f);
  f32x4 gv = ((const f32x4*)gamma)[l];
  f32x4 bv = ((const f32x4*)beta)[l];
  f32x4 o;
#pragma unroll
  for (int c = 0; c < 4; ++c) o[c] = (y[c] - mean) * rstd * gv[c] + bv[c];
  ((f32x4*)(out + base))[l] = o;
}

// ---------------- launch ----------------
extern "C" void kernel_launch(void* const* d_in, const int* in_sizes, int n_in, void* d_out,
                              int out_size, void* d_ws, size_t ws_size, hipStream_t stream) {
  const float* x = (const float*)d_in[0];
  const float* eps = (const float*)d_in[1];
  const float* Wg = (const float*)d_in[18];
  const float* bg = (const float*)d_in[19];
  const float* gamma = (const float*)d_in[20];
  const float* beta = (const float*)d_in[21];

  char* ws = (char*)d_ws;
  bf16* x16 = (bf16*)(ws);                  // 8 MB
  bf16* q16 = (bf16*)(ws + 8388608);        // 8 MB
  bf16* k16 = (bf16*)(ws + 16777216);       // 8 MB
  bf16* v16 = (bf16*)(ws + 25165824);       // 8 MB
  bf16* vt16 = (bf16*)(ws + 33554432);      // 8 MB
  bf16* h16 = (bf16*)(ws + 41943040);       // 8 MB
  bf16* w16 = (bf16*)(ws + 50331648);       // 1 MB (8 x 256x256 bf16)
  float* gpart = (float*)(ws + 51380224);   // 256 KB

  float* out = (float*)d_out;
  float* mu = out + 4194304;
  float* lv = out + 8388608;
  float* pg = out + 12582912;

  WPtrs wp;
  for (int i = 0; i < 8; ++i) wp.p[i] = (const float*)d_in[2 + i];
  cast_all_kernel<<<4608, 256, 0, stream>>>((const f32x4*)x, wp, (ushort4*)x16, (ushort4*)w16);

  GemmIO io1;
  io1.bias[0] = (const float*)d_in[10];
  io1.bias[1] = (const float*)d_in[11];
  io1.bias[2] = (const float*)d_in[12];
  io1.out[0] = q16; io1.out[1] = k16; io1.out[2] = v16;
  gemm_kernel<bf16><<<dim3(128, 2, 3), 256, 0, stream>>>(x16, w16, io1);
  transpose_kernel<<<dim3(64, 4, 4), 256, 0, stream>>>(v16, vt16);
  flash_kernel<<<256, 512, 0, stream>>>(q16, k16, vt16, h16);

  GemmIO io2;
  io2.bias[0] = (const float*)d_in[13];
  io2.bias[1] = (const float*)d_in[14];
  io2.bias[2] = (const float*)d_in[15];
  io2.out[0] = q16; io2.out[1] = k16; io2.out[2] = v16;
  gemm_kernel<bf16><<<dim3(128, 2, 3), 256, 0, stream>>>(h16, w16 + 3 * 65536, io2);
  transpose_kernel<<<dim3(64, 4, 4), 256, 0, stream>>>(v16, vt16);
  flash_kernel<<<256, 512, 0, stream>>>(q16, k16, vt16, h16);

  GemmIO io3;
  io3.bias[0] = (const float*)d_in[16];
  io3.bias[1] = (const float*)d_in[17];
  io3.bias[2] = nullptr;
  io3.out[0] = mu; io3.out[1] = lv; io3.out[2] = nullptr;
  gemm_kernel<float><<<dim3(128, 2, 2), 256, 0, stream>>>(h16, w16 + 6 * 65536, io3);

  gate_partial<<<dim3(64, 4), 256, 0, stream>>>(h16, gpart);
  gate_final<<<4, 256, 0, stream>>>(gpart, Wg, bg, pg);
  epilogue_kernel<<<16384, 64, 0, stream>>>(x, eps, mu, lv, gamma, beta, out);
}

// Round 7
// 367.186 us; speedup vs baseline: 1.4555x; 1.4555x over previous
//
#include <hip/hip_runtime.h>
#include <hip/hip_bf16.h>
#include <cstdint>
#include <cstddef>

// Problem: B=4, S=4096, D=256 two-layer full attention + VAE head. fp32 I/O.
// Strategy: bf16 MFMA everywhere GEMM-shaped; fp32 softmax/epilogue.

#define S_LEN 4096
#define DMODEL 256
#define NBATCH 4
#define MTOT (NBATCH * S_LEN)  // 16384

typedef __bf16 bf16;
typedef __bf16 bf16x8 __attribute__((ext_vector_type(8)));
typedef float f32x4 __attribute__((ext_vector_type(4)));
typedef float f32x16 __attribute__((ext_vector_type(16)));

__device__ __forceinline__ f32x4 mfma16(bf16x8 a, bf16x8 b, f32x4 c) {
  return __builtin_amdgcn_mfma_f32_16x16x32_bf16(a, b, c, 0, 0, 0);
}
__device__ __forceinline__ f32x16 mfma32(bf16x8 a, bf16x8 b, f32x16 c) {
  return __builtin_amdgcn_mfma_f32_32x32x16_bf16(a, b, c, 0, 0, 0);
}

// Async global->LDS, 16B per lane. LDS dest semantics: wave-uniform base + lane*16.
__device__ __forceinline__ void async16(bf16* lds, const bf16* g) {
  __builtin_amdgcn_global_load_lds(
      (const __attribute__((address_space(1))) unsigned int*)g,
      (__attribute__((address_space(3))) unsigned int*)lds, 16, 0, 0);
}

__device__ __forceinline__ unsigned short f2bfbits(float f) {
  return __builtin_bit_cast(unsigned short, (bf16)f);
}

// ---------------- cast kernel (x + 8 weight mats in one launch) ----------------
struct WPtrs { const float* p[8]; };

__global__ void cast_all_kernel(const f32x4* __restrict__ x, WPtrs wp,
                                ushort4* __restrict__ x16, ushort4* __restrict__ w16) {
  int bx = blockIdx.x, t = threadIdx.x;
  const f32x4* src;
  ushort4* dst;
  if (bx < 4096) {
    src = x + (size_t)bx * 256 + t;
    dst = x16 + (size_t)bx * 256 + t;
  } else {
    int r = bx - 4096;
    int m = r >> 6;
    int i = (r & 63) * 256 + t;
    src = (const f32x4*)wp.p[m] + i;
    dst = w16 + (size_t)m * 16384 + i;
  }
  f32x4 v = *src;
  ushort4 o;
  o.x = f2bfbits(v[0]); o.y = f2bfbits(v[1]); o.z = f2bfbits(v[2]); o.w = f2bfbits(v[3]);
  *dst = o;
}

// ---------------- GEMM: out[m][n] = sum_k A[m][k]*W[n][k] + bias[n] ----------------
struct GemmIO {
  const float* bias[3];
  void* out[3];
};

template <typename OutT>
__global__ __launch_bounds__(256, 3) void gemm_kernel(const bf16* __restrict__ A,
                                                      const bf16* __restrict__ Wb, GemmIO io) {
  __shared__ bf16 ldsA[128 * 64];
  __shared__ bf16 ldsB[128 * 64];
  const int t = threadIdx.x;
  const int m0 = blockIdx.x * 128;
  const int n0 = blockIdx.y * 128;
  const bf16* W = Wb + (size_t)blockIdx.z * 65536;
  const int w = t >> 6, l = t & 63, lm = l & 15, q = l >> 4;
  const int wr = (w >> 1) * 64, wc = (w & 1) * 64;

  f32x4 acc[4][4] = {};
#pragma unroll 1
  for (int it = 0; it < 4; ++it) {
    const int k0 = it * 64;
#pragma unroll
    for (int c = 0; c < 4; ++c) {
      int i = c * 256 + t;
      int r = i >> 3, c8 = (i & 7) ^ (r & 7);
      async16(&ldsA[i * 8], A + (size_t)(m0 + r) * 256 + k0 + c8 * 8);
    }
#pragma unroll
    for (int c = 0; c < 4; ++c) {
      int i = c * 256 + t;
      int r = i >> 3, c8 = (i & 7) ^ (r & 7);
      async16(&ldsB[i * 8], W + (size_t)(n0 + r) * 256 + k0 + c8 * 8);
    }
    __syncthreads();
#pragma unroll
    for (int ks = 0; ks < 2; ++ks) {
      bf16x8 af[4], bfr[4];
#pragma unroll
      for (int i = 0; i < 4; ++i) {
        int ra = wr + i * 16 + lm;
        af[i] = *(const bf16x8*)&ldsA[ra * 64 + ((((ks << 2) + q) ^ (ra & 7)) << 3)];
        int rb = wc + i * 16 + lm;
        bfr[i] = *(const bf16x8*)&ldsB[rb * 64 + ((((ks << 2) + q) ^ (rb & 7)) << 3)];
      }
#pragma unroll
      for (int i = 0; i < 4; ++i)
#pragma unroll
        for (int jj = 0; jj < 4; ++jj) acc[i][jj] = mfma16(af[i], bfr[jj], acc[i][jj]);
    }
    __syncthreads();
  }
  const float* bias = io.bias[blockIdx.z];
  OutT* out = (OutT*)io.out[blockIdx.z];
#pragma unroll
  for (int jj = 0; jj < 4; ++jj) {
    int col = n0 + wc + jj * 16 + lm;
    float bv = bias[col];
#pragma unroll
    for (int i = 0; i < 4; ++i) {
      int row = m0 + wr + i * 16 + q * 4;
#pragma unroll
      for (int r = 0; r < 4; ++r)
        out[(size_t)(row + r) * 256 + col] = (OutT)(acc[i][jj][r] + bv);
    }
  }
}

// ---------------- transpose: V [B][S][256] -> Vt [B][256][S] ----------------
__global__ void transpose_kernel(const bf16* __restrict__ src, bf16* __restrict__ dst) {
  __shared__ bf16 tile[64][72];
  int s0 = blockIdx.x * 64, d0 = blockIdx.y * 64;
  size_t boff = (size_t)blockIdx.z * S_LEN * 256;
  size_t boffT = (size_t)blockIdx.z * 256 * S_LEN;
  int t = threadIdx.x;
#pragma unroll
  for (int rep = 0; rep < 16; ++rep) {
    int lin = rep * 256 + t;
    int r = lin >> 6, c = lin & 63;
    tile[r][c] = src[boff + (size_t)(s0 + r) * 256 + d0 + c];
  }
  __syncthreads();
#pragma unroll
  for (int rep = 0; rep < 16; ++rep) {
    int lin = rep * 256 + t;
    int r = lin >> 6, c = lin & 63;
    dst[boffT + (size_t)(d0 + r) * S_LEN + s0 + c] = tile[c][r];
  }
}

// ---------------- flash attention v4b: 32x32x16 MFMA, l via ones-MFMA ----------
// 256 blocks (1/CU), 512 threads = 8 waves = 2/SIMD. BM=64 Q rows, KV tile 128.
// Wave (qg = w&1, sub = w>>1):
//  QK phase: sub = KV quarter. S-strip 32x32 (rows qg*32+, cols sub*32+), K=256.
//            P = exp2(S*CL2) -> LDS strip [qg][sub][32][40] (no max: scores O(1)).
//  PV phase: sub = D quarter. Reads ALL 4 P strips of qg (k = 0..127) and V cols
//            sub*64..+63 -> disjoint 32x64 output per wave: NO merge.
//            l = row-sums of P via ones-B MFMA -> C-layout matches O rows exactly.
// Single K (64KB) / V (64KB) buffers pipelined on the 2 barriers:
//  stageV(j) issued after B1 (V free) overlaps QK(j); stageK(j+1) after B2 overlaps PV(j).
// C/D map (verified): col=lane&31, row=(reg&3)+8*(reg>>2)+4*(lane>>5).
__global__ __launch_bounds__(512, 2) void flash_kernel(const bf16* __restrict__ Q,
                                                       const bf16* __restrict__ K,
                                                       const bf16* __restrict__ Vt,
                                                       bf16* __restrict__ O) {
  __shared__ bf16 ldsK[128 * 256];  // 64KB: 128 kv-rows x 256 d, 32 chunks/row, ^(row&31)
  __shared__ bf16 ldsV[256 * 128];  // 64KB: 256 d-rows x 128 kv, 16 chunks/row, ^(d&15)
  __shared__ bf16 ldsP[8 * 1280];   // 20KB: [qg*4+hs][32][40]

  const int id = blockIdx.x;
  const int xcd = id & 7;
  const int b = xcd >> 1;
  const int qt = (id >> 3) + ((xcd & 1) << 5);  // 0..63

  const bf16* Qb = Q + (size_t)b * S_LEN * 256;
  const bf16* Kb = K + (size_t)b * S_LEN * 256;
  const bf16* Vb = Vt + (size_t)b * 256 * S_LEN;
  bf16* Ob = O + (size_t)b * S_LEN * 256;

  const int t = threadIdx.x, w = t >> 6, lane = t & 63;
  const int m31 = lane & 31, kh = lane >> 5;
  const int qg = w & 1, sub = w >> 1;
  const float CL2 = 0.09016844005556021f;  // log2(e)/sqrt(D) = log2(e)/16

  // staging offsets: 4096 16B-chunks per tile, 8 per thread
  int sld[8], skg[8], svg[8];
#pragma unroll
  for (int it = 0; it < 8; ++it) {
    int c = it * 512 + t;
    sld[it] = c * 8;
    int kr = c >> 5;
    skg[it] = kr * 256 + (((c & 31) ^ (kr & 31)) << 3);
    int d = c >> 4;
    svg[it] = d * S_LEN + (((c & 15) ^ (d & 15)) << 3);
  }
  // K B-frag offsets (j-invariant): n = sub*32 + m31, chunk = ks*2+kh, slot = chunk^(n&31)
  int koff[16];
  {
    const int n = sub * 32 + m31;
#pragma unroll
    for (int ks = 0; ks < 16; ++ks) koff[ks] = n * 256 + (((ks * 2 + kh) ^ (n & 31)) << 3);
  }
  // V B-frag offsets: d = (sub*2+nt2)*32 + m31, chunk = ks*2+kh, slot = chunk^(d&15)
  int voff[2][8];
#pragma unroll
  for (int nt2 = 0; nt2 < 2; ++nt2) {
    const int d = (sub * 2 + nt2) * 32 + m31;
#pragma unroll
    for (int ks = 0; ks < 8; ++ks) voff[nt2][ks] = d * 128 + (((ks * 2 + kh) ^ (d & 15)) << 3);
  }
  // P A-frag offsets: k = ks*16 + kh*8 -> strip hs = k>>5, col k&31
  int poff[8];
#pragma unroll
  for (int ks = 0; ks < 8; ++ks) {
    int kloc = ks * 16 + kh * 8;
    poff[ks] = (qg * 4 + (kloc >> 5)) * 1280 + m31 * 40 + (kloc & 31);
  }
  // P store base: strip (qg,sub), row offset 4*kh, col m31
  bf16* ps = &ldsP[(qg * 4 + sub) * 1280 + (kh * 4) * 40 + m31];

  // Q A-frags persistent: rows qt*64 + qg*32 + m31, k = ks*16 + kh*8 + i
  bf16x8 qf[16];
  {
    const bf16* qrow = Qb + (size_t)(qt * 64 + qg * 32 + m31) * 256 + kh * 8;
#pragma unroll
    for (int ks = 0; ks < 16; ++ks) qf[ks] = *(const bf16x8*)(qrow + ks * 16);
  }
  bf16x8 ones;
#pragma unroll
  for (int i = 0; i < 8; ++i) ones[i] = (bf16)1.0f;

  f32x16 o_acc[2] = {};
  f32x16 l_vec = {};

  // prologue: stage K(0)
#pragma unroll
  for (int it = 0; it < 8; ++it) async16(&ldsK[0] + sld[it], Kb + skg[it]);

#pragma unroll 1
  for (int j = 0; j < 32; ++j) {
    __syncthreads();  // B1: stageK(j) drained; PV(j-1) done (V + P strips free)
    {                 // stage V(j), overlaps QK(j)
      const bf16* vg = Vb + j * 128;
#pragma unroll
      for (int it = 0; it < 8; ++it) async16(&ldsV[0] + sld[it], vg + svg[it]);
    }
    // QK(j): 32x32 S-strip, K=256
    f32x16 s = {};
#pragma unroll
    for (int ks = 0; ks < 16; ++ks) {
      bf16x8 kf = *(const bf16x8*)(&ldsK[0] + koff[ks]);
      s = mfma32(qf[ks], kf, s);
    }
    // P = exp2(S*CL2) -> strip (C-layout rows)
#pragma unroll
    for (int reg = 0; reg < 16; ++reg) {
      const int row = (reg & 3) + 8 * (reg >> 2);
      ps[row * 40] = (bf16)__builtin_amdgcn_exp2f(s[reg] * CL2);
    }
    __syncthreads();  // B2: stageV(j) drained; QK(j) done (K free); P visible
    if (j + 1 < 32) {  // stage K(j+1), overlaps PV(j)
      const bf16* kg = Kb + (size_t)(j + 1) * (128 * 256);
#pragma unroll
      for (int it = 0; it < 8; ++it) async16(&ldsK[0] + sld[it], kg + skg[it]);
    }
    // PV(j): rows qg*32+, cols sub*64..+63, k = full 128 kv; l via ones-MFMA
    bf16x8 pa[8];
#pragma unroll
    for (int ks = 0; ks < 8; ++ks) pa[ks] = *(const bf16x8*)(&ldsP[0] + poff[ks]);
#pragma unroll
    for (int ks = 0; ks < 8; ++ks) l_vec = mfma32(pa[ks], ones, l_vec);
#pragma unroll
    for (int nt2 = 0; nt2 < 2; ++nt2)
#pragma unroll
      for (int ks = 0; ks < 8; ++ks) {
        bf16x8 vf = *(const bf16x8*)(&ldsV[0] + voff[nt2][ks]);
        o_acc[nt2] = mfma32(pa[ks], vf, o_acc[nt2]);
      }
  }

  // epilogue: l_vec C-layout rows match o_acc rows exactly -> no shuffles
  bf16* orow = Ob + (size_t)(qt * 64 + qg * 32) * 256 + sub * 64;
#pragma unroll
  for (int reg = 0; reg < 16; ++reg) {
    const int row = (reg & 3) + 8 * (reg >> 2) + 4 * kh;
    const float linv = 1.0f / l_vec[reg];
    orow[(size_t)row * 256 + m31] = (bf16)(o_acc[0][reg] * linv);
    orow[(size_t)row * 256 + 32 + m31] = (bf16)(o_acc[1][reg] * linv);
  }
}

// ---------------- gate: mean over S then dot Wg + sigmoid ----------------
__global__ __launch_bounds__(256) void gate_partial(const bf16* __restrict__ h,
                                                    float* __restrict__ part) {
  int bb = blockIdx.y;
  const bf16* hb = h + (size_t)bb * S_LEN * 256 + (size_t)blockIdx.x * 64 * 256;
  int t = threadIdx.x;
  float acc = 0.f;
#pragma unroll 4
  for (int s = 0; s < 64; ++s) acc += (float)hb[s * 256 + t];
  part[((size_t)bb * 64 + blockIdx.x) * 256 + t] = acc;
}

__global__ __launch_bounds__(256) void gate_final(const float* __restrict__ part,
                                                  const float* __restrict__ Wg,
                                                  const float* __restrict__ bg,
                                                  float* __restrict__ pg) {
  int bb = blockIdx.x, t = threadIdx.x;
  const float* p = part + (size_t)bb * 64 * 256;
  float acc = 0.f;
#pragma unroll 4
  for (int c = 0; c < 64; ++c) acc += p[c * 256 + t];
  acc *= Wg[t] * (1.0f / 4096.0f);
  __shared__ float red[256];
  red[t] = acc;
  __syncthreads();
  if (t < 64) {
    float a = red[t] + red[t + 64] + red[t + 128] + red[t + 192];
#pragma unroll
    for (int d = 1; d < 64; d <<= 1) a += __shfl_xor(a, d, 64);
    if (t == 0) pg[bb] = 1.0f / (1.0f + __expf(-(a + bg[0])));
  }
}

// ---------------- fused reparam + ELU + residual + LayerNorm ----------------
// 256 threads = 4 rows/block; shuffle reductions stay within each 64-lane wave.
__global__ __launch_bounds__(256) void epilogue_kernel(const float* __restrict__ x,
                                                       const float* __restrict__ eps,
                                                       const float* __restrict__ mu,
                                                       const float* __restrict__ lv,
                                                       const float* __restrict__ gamma,
                                                       const float* __restrict__ beta,
                                                       float* __restrict__ out) {
  size_t base = (size_t)blockIdx.x * 1024 + (threadIdx.x >> 6) * 256;
  int l = threadIdx.x & 63;
  f32x4 xv = ((const f32x4*)(x + base))[l];
  f32x4 ev = ((const f32x4*)(eps + base))[l];
  f32x4 mv = ((const f32x4*)(mu + base))[l];
  f32x4 vv = ((const f32x4*)(lv + base))[l];
  f32x4 y;
  float s = 0.f, s2 = 0.f;
#pragma unroll
  for (int c = 0; c < 4; ++c) {
    float z = mv[c] + ev[c] * __expf(0.5f * vv[c]);
    z = z > 0.f ? z : (__expf(z) - 1.f);
    float yy = xv[c] + z;
    y[c] = yy;
    s += yy;
    s2 += yy * yy;
  }
#pragma unroll
  for (int d = 1; d < 64; d <<= 1) {
    s += __shfl_xor(s, d, 64);
    s2 += __shfl_xor(s2, d, 64);
  }
  float mean = s * (1.f / 256.f);
  float var = s2 * (1.f / 256.f) - mean * mean;
  float rstd = rsqrtf(var + 1e-5f);
  f32x4 gv = ((const f32x4*)gamma)[l];
  f32x4 bv = ((const f32x4*)beta)[l];
  f32x4 o;
#pragma unroll
  for (int c = 0; c < 4; ++c) o[c] = (y[c] - mean) * rstd * gv[c] + bv[c];
  ((f32x4*)(out + base))[l] = o;
}

// ---------------- launch ----------------
extern "C" void kernel_launch(void* const* d_in, const int* in_sizes, int n_in, void* d_out,
                              int out_size, void* d_ws, size_t ws_size, hipStream_t stream) {
  const float* x = (const float*)d_in[0];
  const float* eps = (const float*)d_in[1];
  const float* Wg = (const float*)d_in[18];
  const float* bg = (const float*)d_in[19];
  const float* gamma = (const float*)d_in[20];
  const float* beta = (const float*)d_in[21];

  char* ws = (char*)d_ws;
  bf16* x16 = (bf16*)(ws);                  // 8 MB
  bf16* q16 = (bf16*)(ws + 8388608);        // 8 MB
  bf16* k16 = (bf16*)(ws + 16777216);       // 8 MB
  bf16* v16 = (bf16*)(ws + 25165824);       // 8 MB
  bf16* vt16 = (bf16*)(ws + 33554432);      // 8 MB
  bf16* h16 = (bf16*)(ws + 41943040);       // 8 MB
  bf16* w16 = (bf16*)(ws + 50331648);       // 1 MB (8 x 256x256 bf16)
  float* gpart = (float*)(ws + 51380224);   // 256 KB

  float* out = (float*)d_out;
  float* mu = out + 4194304;
  float* lv = out + 8388608;
  float* pg = out + 12582912;

  WPtrs wp;
  for (int i = 0; i < 8; ++i) wp.p[i] = (const float*)d_in[2 + i];
  cast_all_kernel<<<4608, 256, 0, stream>>>((const f32x4*)x, wp, (ushort4*)x16, (ushort4*)w16);

  GemmIO io1;
  io1.bias[0] = (const float*)d_in[10];
  io1.bias[1] = (const float*)d_in[11];
  io1.bias[2] = (const float*)d_in[12];
  io1.out[0] = q16; io1.out[1] = k16; io1.out[2] = v16;
  gemm_kernel<bf16><<<dim3(128, 2, 3), 256, 0, stream>>>(x16, w16, io1);
  transpose_kernel<<<dim3(64, 4, 4), 256, 0, stream>>>(v16, vt16);
  flash_kernel<<<256, 512, 0, stream>>>(q16, k16, vt16, h16);

  GemmIO io2;
  io2.bias[0] = (const float*)d_in[13];
  io2.bias[1] = (const float*)d_in[14];
  io2.bias[2] = (const float*)d_in[15];
  io2.out[0] = q16; io2.out[1] = k16; io2.out[2] = v16;
  gemm_kernel<bf16><<<dim3(128, 2, 3), 256, 0, stream>>>(h16, w16 + 3 * 65536, io2);
  transpose_kernel<<<dim3(64, 4, 4), 256, 0, stream>>>(v16, vt16);
  flash_kernel<<<256, 512, 0, stream>>>(q16, k16, vt16, h16);

  GemmIO io3;
  io3.bias[0] = (const float*)d_in[16];
  io3.bias[1] = (const float*)d_in[17];
  io3.bias[2] = nullptr;
  io3.out[0] = mu; io3.out[1] = lv; io3.out[2] = nullptr;
  gemm_kernel<float><<<dim3(128, 2, 2), 256, 0, stream>>>(h16, w16 + 6 * 65536, io3);

  gate_partial<<<dim3(64, 4), 256, 0, stream>>>(h16, gpart);
  gate_final<<<4, 256, 0, stream>>>(gpart, Wg, bg, pg);
  epilogue_kernel<<<4096, 256, 0, stream>>>(x, eps, mu, lv, gamma, beta, out);
}